// Round 4
// baseline (122.813 us; speedup 1.0000x reference)
//
#include <hip/hip_runtime.h>
#include <hip/hip_bf16.h>

#define B_ 4
#define N_ 20000
#define D_ 128
#define E_ 100000
#define NT_ 1250     // 16-node tiles (20000/16 exact)
#define GX_ 313      // ceil(NT_/4)

typedef __attribute__((ext_vector_type(8))) short bf16x8;
typedef __attribute__((ext_vector_type(4))) float f32x4;

// ws layout (float units):
// [0]              flag (int)
// [8,12)           qg (B_)
// [256,8448)       w7f: 2048 x bf16x8 (32 KB), MFMA B-fragment order
// [8448,648448)    gpart[1250][512]  (per-tile g partials, b*128+col)
// [648448,728448)  qi (B x N)
// [728448,808448)  qj (B x N)

__global__ __launch_bounds__(256) void k_prep(
    const float* __restrict__ W7, const unsigned* __restrict__ ew,
    int* __restrict__ flag, bf16x8* __restrict__ w7f)
{
    const int bx = blockIdx.x, t = threadIdx.x;
    if (bx == 8) {
        if (t < 64) {
            unsigned v = ew[2 * t + 1];      // high words if int64 (all zero)
            unsigned long long any = __ballot(v != 0u);
            if (t == 0) *flag = (any == 0ULL) ? 1 : 0;
        }
        return;
    }
    int f = bx * 256 + t;                    // 0..2047
    int tt = f >> 8, s = (f >> 6) & 3, lane = f & 63;
    int kg = lane >> 4, rc = lane & 15;
    int col = tt * 16 + rc, k0 = s * 32 + kg * 8;
    union { bf16x8 v; __hip_bfloat16 h[8]; } pk;
    #pragma unroll
    for (int m = 0; m < 8; ++m)
        pk.h[m] = __float2bfloat16(W7[(k0 + m) * D_ + col]);
    w7f[f] = pk.v;
}

__global__ __launch_bounds__(256) void k_main(
    const float* __restrict__ emb, const bf16x8* __restrict__ w7f,
    const float* __restrict__ w5, float* __restrict__ gpart,
    float* __restrict__ qi, float* __restrict__ qj)
{
    __shared__ bf16x8 sB[2048];   // fragment order: idx = tt*256 + s*64 + lane

    const int t = threadIdx.x, b = blockIdx.y;
    const int wv = t >> 6, lane = t & 63, rc = lane & 15, kg = lane >> 4;
    const int tile = blockIdx.x * 4 + wv;
    const int tc = (tile < NT_) ? tile : (NT_ - 1);

    // ---- issue ALL A loads first (8 independent dwordx4, fly under B-stage)
    const float4* p = (const float4*)(emb + (size_t)b * N_ * D_)
                      + ((size_t)(tc * 16 + rc)) * 32 + kg * 2;
    float4 a[8];
    #pragma unroll
    for (int s = 0; s < 4; ++s) { a[2*s] = p[s*8]; a[2*s+1] = p[s*8+1]; }

    // ---- stage B (coalesced uint4, L2-resident source)
    {
        const uint4* src = (const uint4*)w7f;
        uint4* dst = (uint4*)sB;
        #pragma unroll
        for (int i = 0; i < 8; ++i) dst[t + 256 * i] = src[t + 256 * i];
    }
    __syncthreads();

    // ---- convert to bf16 fragments (A values stay live in a[] for g)
    bf16x8 pk[4];
    #pragma unroll
    for (int s = 0; s < 4; ++s) {
        union { bf16x8 v; __hip_bfloat16 h[8]; } u;
        float4 x = a[2*s], y = a[2*s+1];
        u.h[0] = __float2bfloat16(x.x); u.h[1] = __float2bfloat16(x.y);
        u.h[2] = __float2bfloat16(x.z); u.h[3] = __float2bfloat16(x.w);
        u.h[4] = __float2bfloat16(y.x); u.h[5] = __float2bfloat16(y.y);
        u.h[6] = __float2bfloat16(y.z); u.h[7] = __float2bfloat16(y.w);
        pk[s] = u.v;
    }

    // ---- MFMA: 16 nodes x 128 cols, K=128 (32 MFMA/wave)
    f32x4 acc[8] = {};
    #pragma unroll
    for (int s = 0; s < 4; ++s) {
        #pragma unroll
        for (int tt = 0; tt < 8; ++tt) {
            bf16x8 bb = sB[tt * 256 + s * 64 + lane];
            acc[tt] = __builtin_amdgcn_mfma_f32_16x16x32_bf16(pk[s], bb, acc[tt], 0, 0, 0);
        }
    }

    // ---- epilogue: leaky, dot w5_i/w5_j, reduce over cols (rc), store
    // D layout: col = tt*16 + rc, row = kg*4 + reg
    float qip[4] = {0,0,0,0}, qjp[4] = {0,0,0,0};
    #pragma unroll
    for (int tt = 0; tt < 8; ++tt) {
        int col = tt * 16 + rc;
        float wi = w5[D_ + col], wj = w5[2 * D_ + col];
        #pragma unroll
        for (int r = 0; r < 4; ++r) {
            float pv = acc[tt][r];
            float lr = (pv >= 0.f) ? pv : 0.01f * pv;
            qip[r] += lr * wi; qjp[r] += lr * wj;
        }
    }
    #pragma unroll
    for (int m = 1; m < 16; m <<= 1) {
        #pragma unroll
        for (int r = 0; r < 4; ++r) {
            qip[r] += __shfl_xor(qip[r], m);
            qjp[r] += __shfl_xor(qjp[r], m);
        }
    }
    if (tile < NT_ && rc == 0) {
        #pragma unroll
        for (int r = 0; r < 4; ++r) {
            int node = tile * 16 + kg * 4 + r;
            qi[b * N_ + node] = qip[r];
            qj[b * N_ + node] = qjp[r];
        }
    }

    // ---- g partials: reduce a[] over the 16 rows (rc), scatter-store (NO atomics)
    #pragma unroll
    for (int m = 1; m < 16; m <<= 1) {
        #pragma unroll
        for (int i = 0; i < 8; ++i) {
            a[i].x += __shfl_xor(a[i].x, m);
            a[i].y += __shfl_xor(a[i].y, m);
            a[i].z += __shfl_xor(a[i].z, m);
            a[i].w += __shfl_xor(a[i].w, m);
        }
    }
    if (tile < NT_ && rc == 0) {
        float* gp = gpart + (size_t)tile * 512 + b * 128;
        #pragma unroll
        for (int s = 0; s < 4; ++s) {
            int c0 = s * 32 + kg * 8;
            *reinterpret_cast<float4*>(gp + c0)     = a[2*s];
            *reinterpret_cast<float4*>(gp + c0 + 4) = a[2*s+1];
        }
    }
}

__global__ __launch_bounds__(256) void k_qg(
    const float* __restrict__ gpart, const float* __restrict__ W6,
    const float* __restrict__ w5, const float* __restrict__ wno,
    float* __restrict__ qg, float* __restrict__ out)
{
    __shared__ float sg[128];
    __shared__ float sp2[2][128];
    __shared__ float sr[2], srn[2];
    const int b = blockIdx.x, t = threadIdx.x;
    const int col = t & 127, h = t >> 7;

    float s = 0.f;
    #pragma unroll 4
    for (int i = 0; i < 625; ++i) {
        int tile = h * 625 + i;
        s += gpart[(size_t)tile * 512 + b * 128 + col];
    }
    sp2[h][col] = s;
    __syncthreads();
    if (t < 128) sg[t] = sp2[0][t] + sp2[1][t];
    __syncthreads();

    float pv = 0.f;
    #pragma unroll 8
    for (int d = h * 64; d < h * 64 + 64; ++d)
        pv += sg[d] * W6[d * D_ + col];
    __syncthreads();
    sp2[h][col] = pv;
    __syncthreads();

    if (t < 128) {
        float pp = sp2[0][t] + sp2[1][t];
        float lr = (pp >= 0.f) ? pp : 0.01f * pp;
        float vq = lr * w5[t];       // w5_g
        float vn = sg[t] * wno[t];   // noop
        #pragma unroll
        for (int m = 1; m < 64; m <<= 1) {
            vq += __shfl_xor(vq, m);
            vn += __shfl_xor(vn, m);
        }
        if ((t & 63) == 0) { sr[t >> 6] = vq; srn[t >> 6] = vn; }
    }
    __syncthreads();
    if (t == 0) {
        qg[b] = sr[0] + sr[1];
        out[(size_t)b * (E_ + 1) + E_] = srn[0] + srn[1];
    }
}

__global__ __launch_bounds__(256) void k_edge(
    const int* __restrict__ edges, const int* __restrict__ flag,
    const float* __restrict__ qg, const float* __restrict__ qi,
    const float* __restrict__ qj, float* __restrict__ out)
{
    int e = blockIdx.x * 256 + threadIdx.x;
    if (e >= E_) return;
    int u, v;
    if (*flag) { int4 w = ((const int4*)edges)[e]; u = w.x; v = w.z; }
    else       { int2 w = ((const int2*)edges)[e]; u = w.x; v = w.y; }
    float q0 = qg[0], q1 = qg[1], q2 = qg[2], q3 = qg[3];
    out[0 * (size_t)(E_ + 1) + e] = q0 + qi[0 * N_ + u] + qj[0 * N_ + v];
    out[1 * (size_t)(E_ + 1) + e] = q1 + qi[1 * N_ + u] + qj[1 * N_ + v];
    out[2 * (size_t)(E_ + 1) + e] = q2 + qi[2 * N_ + u] + qj[2 * N_ + v];
    out[3 * (size_t)(E_ + 1) + e] = q3 + qi[3 * N_ + u] + qj[3 * N_ + v];
}

extern "C" void kernel_launch(void* const* d_in, const int* in_sizes, int n_in,
                              void* d_out, int out_size, void* d_ws, size_t ws_size,
                              hipStream_t stream)
{
    const float* emb   = (const float*)d_in[0];
    const int*   edges = (const int*)d_in[1];
    const float* W6    = (const float*)d_in[2];
    const float* W7    = (const float*)d_in[3];
    const float* w5    = (const float*)d_in[4];
    const float* wno   = (const float*)d_in[5];
    float* out = (float*)d_out;

    float* W = (float*)d_ws;
    int*    flag  = (int*)W;
    float*  qg    = W + 8;
    bf16x8* w7f   = (bf16x8*)(W + 256);
    float*  gpart = W + 8448;
    float*  qi    = W + 648448;
    float*  qj    = W + 728448;

    hipLaunchKernelGGL(k_prep, dim3(9), dim3(256), 0, stream,
                       W7, (const unsigned*)edges, flag, w7f);
    hipLaunchKernelGGL(k_main, dim3(GX_, B_), dim3(256), 0, stream,
                       emb, w7f, w5, gpart, qi, qj);
    hipLaunchKernelGGL(k_qg, dim3(B_), dim3(256), 0, stream,
                       gpart, W6, w5, wno, qg, out);
    hipLaunchKernelGGL(k_edge, dim3((E_ + 255) / 256), dim3(256), 0, stream,
                       edges, flag, qg, qi, qj, out);
}

// Round 5
// 39.351 us; speedup vs baseline: 3.1210x; 3.1210x over previous
//
#include <hip/hip_runtime.h>
#include <hip/hip_bf16.h>

#define B_ 4
#define N_ 20000
#define D_ 128
#define E_ 100000
#define NT_ 1250     // 16-node tiles (20000/16 exact)
#define GX_ 313      // ceil(NT_/4)

typedef __attribute__((ext_vector_type(8))) short bf16x8;
typedef __attribute__((ext_vector_type(4))) float f32x4;

// ws layout (float units):
// [0]              flag (int)
// [8,12)           qg (B_)
// [128,640)        g (B_ x D_) final sums
// [1024,9216)      w7f: 2048 x bf16x8 (32 KB), MFMA B-fragment order
// [9216,649216)    gpart[1250][512]  (per-tile g partials, b*128+col)
// [649216,729216)  qi (B x N)
// [729216,809216)  qj (B x N)

__global__ __launch_bounds__(256) void k_prep(
    const float* __restrict__ W7, const unsigned* __restrict__ ew,
    int* __restrict__ flag, float* __restrict__ g, bf16x8* __restrict__ w7f)
{
    const int bx = blockIdx.x, t = threadIdx.x;
    if (bx == 8) {
        g[t] = 0.f; g[t + 256] = 0.f;
        if (t < 64) {
            unsigned v = ew[2 * t + 1];      // high words if int64 (all zero)
            unsigned long long any = __ballot(v != 0u);
            if (t == 0) *flag = (any == 0ULL) ? 1 : 0;
        }
        return;
    }
    int f = bx * 256 + t;                    // 0..2047
    int tt = f >> 8, s = (f >> 6) & 3, lane = f & 63;
    int kg = lane >> 4, rc = lane & 15;
    int col = tt * 16 + rc, k0 = s * 32 + kg * 8;
    union { bf16x8 v; __hip_bfloat16 h[8]; } pk;
    #pragma unroll
    for (int m = 0; m < 8; ++m)
        pk.h[m] = __float2bfloat16(W7[(k0 + m) * D_ + col]);
    w7f[f] = pk.v;
}

__global__ __launch_bounds__(256) void k_main(
    const float* __restrict__ emb, const bf16x8* __restrict__ w7f,
    const float* __restrict__ w5, float* __restrict__ gpart,
    float* __restrict__ qi, float* __restrict__ qj)
{
    __shared__ bf16x8 sB[2048];   // fragment order: idx = tt*256 + s*64 + lane

    const int t = threadIdx.x, b = blockIdx.y;
    const int wv = t >> 6, lane = t & 63, rc = lane & 15, kg = lane >> 4;
    const int tile = blockIdx.x * 4 + wv;
    const int tc = (tile < NT_) ? tile : (NT_ - 1);

    // ---- issue ALL A loads first (8 independent dwordx4, fly under B-stage)
    const float4* p = (const float4*)(emb + (size_t)b * N_ * D_)
                      + ((size_t)(tc * 16 + rc)) * 32 + kg * 2;
    float4 a[8];
    #pragma unroll
    for (int s = 0; s < 4; ++s) { a[2*s] = p[s*8]; a[2*s+1] = p[s*8+1]; }

    // ---- stage B (coalesced uint4, L2-resident source)
    {
        const uint4* src = (const uint4*)w7f;
        uint4* dst = (uint4*)sB;
        #pragma unroll
        for (int i = 0; i < 8; ++i) dst[t + 256 * i] = src[t + 256 * i];
    }
    __syncthreads();

    // ---- convert to bf16 fragments (A values stay live in a[] for g)
    bf16x8 pk[4];
    #pragma unroll
    for (int s = 0; s < 4; ++s) {
        union { bf16x8 v; __hip_bfloat16 h[8]; } u;
        float4 x = a[2*s], y = a[2*s+1];
        u.h[0] = __float2bfloat16(x.x); u.h[1] = __float2bfloat16(x.y);
        u.h[2] = __float2bfloat16(x.z); u.h[3] = __float2bfloat16(x.w);
        u.h[4] = __float2bfloat16(y.x); u.h[5] = __float2bfloat16(y.y);
        u.h[6] = __float2bfloat16(y.z); u.h[7] = __float2bfloat16(y.w);
        pk[s] = u.v;
    }

    // ---- MFMA: 16 nodes x 128 cols, K=128 (32 MFMA/wave)
    f32x4 acc[8] = {};
    #pragma unroll
    for (int s = 0; s < 4; ++s) {
        #pragma unroll
        for (int tt = 0; tt < 8; ++tt) {
            bf16x8 bb = sB[tt * 256 + s * 64 + lane];
            acc[tt] = __builtin_amdgcn_mfma_f32_16x16x32_bf16(pk[s], bb, acc[tt], 0, 0, 0);
        }
    }

    // ---- epilogue: leaky, dot w5_i/w5_j, reduce over cols (rc), store
    // D layout: col = tt*16 + rc, row = kg*4 + reg
    float qip[4] = {0,0,0,0}, qjp[4] = {0,0,0,0};
    #pragma unroll
    for (int tt = 0; tt < 8; ++tt) {
        int col = tt * 16 + rc;
        float wi = w5[D_ + col], wj = w5[2 * D_ + col];
        #pragma unroll
        for (int r = 0; r < 4; ++r) {
            float pv = acc[tt][r];
            float lr = (pv >= 0.f) ? pv : 0.01f * pv;
            qip[r] += lr * wi; qjp[r] += lr * wj;
        }
    }
    #pragma unroll
    for (int m = 1; m < 16; m <<= 1) {
        #pragma unroll
        for (int r = 0; r < 4; ++r) {
            qip[r] += __shfl_xor(qip[r], m);
            qjp[r] += __shfl_xor(qjp[r], m);
        }
    }
    if (tile < NT_ && rc == 0) {
        #pragma unroll
        for (int r = 0; r < 4; ++r) {
            int node = tile * 16 + kg * 4 + r;
            qi[b * N_ + node] = qip[r];
            qj[b * N_ + node] = qjp[r];
        }
    }

    // ---- g partials: reduce a[] over the 16 rows (rc), scatter-store (NO atomics)
    #pragma unroll
    for (int m = 1; m < 16; m <<= 1) {
        #pragma unroll
        for (int i = 0; i < 8; ++i) {
            a[i].x += __shfl_xor(a[i].x, m);
            a[i].y += __shfl_xor(a[i].y, m);
            a[i].z += __shfl_xor(a[i].z, m);
            a[i].w += __shfl_xor(a[i].w, m);
        }
    }
    if (tile < NT_ && rc == 0) {
        float* gp = gpart + (size_t)tile * 512 + b * 128;
        #pragma unroll
        for (int s = 0; s < 4; ++s) {
            int c0 = s * 32 + kg * 8;
            *reinterpret_cast<float4*>(gp + c0)     = a[2*s];
            *reinterpret_cast<float4*>(gp + c0 + 4) = a[2*s+1];
        }
    }
}

// parallel reduction of gpart: 50 blocks x 512 threads, 25 tiles each, coalesced
__global__ __launch_bounds__(512) void k_greduce(
    const float* __restrict__ gpart, float* __restrict__ g)
{
    const int t = threadIdx.x;          // column 0..511
    const int c0 = blockIdx.x * 25;     // tile chunk
    float s = 0.f;
    #pragma unroll 5
    for (int i = 0; i < 25; ++i)
        s += gpart[(size_t)(c0 + i) * 512 + t];
    atomicAdd(&g[t], s);
}

__global__ __launch_bounds__(256) void k_qg(
    const float* __restrict__ g, const float* __restrict__ W6,
    const float* __restrict__ w5, const float* __restrict__ wno,
    float* __restrict__ qg, float* __restrict__ out)
{
    __shared__ float sg[128];
    __shared__ float sp2[2][128];
    __shared__ float sr[2], srn[2];
    const int b = blockIdx.x, t = threadIdx.x;
    const int col = t & 127, h = t >> 7;

    if (t < 128) sg[t] = g[b * D_ + t];
    __syncthreads();

    float pv = 0.f;
    #pragma unroll 8
    for (int d = h * 64; d < h * 64 + 64; ++d)
        pv += sg[d] * W6[d * D_ + col];
    sp2[h][col] = pv;
    __syncthreads();

    if (t < 128) {
        float pp = sp2[0][t] + sp2[1][t];
        float lr = (pp >= 0.f) ? pp : 0.01f * pp;
        float vq = lr * w5[t];       // w5_g
        float vn = sg[t] * wno[t];   // noop
        #pragma unroll
        for (int m = 1; m < 64; m <<= 1) {
            vq += __shfl_xor(vq, m);
            vn += __shfl_xor(vn, m);
        }
        if ((t & 63) == 0) { sr[t >> 6] = vq; srn[t >> 6] = vn; }
    }
    __syncthreads();
    if (t == 0) {
        qg[b] = sr[0] + sr[1];
        out[(size_t)b * (E_ + 1) + E_] = srn[0] + srn[1];
    }
}

__global__ __launch_bounds__(256) void k_edge(
    const int* __restrict__ edges, const int* __restrict__ flag,
    const float* __restrict__ qg, const float* __restrict__ qi,
    const float* __restrict__ qj, float* __restrict__ out)
{
    int e = blockIdx.x * 256 + threadIdx.x;
    if (e >= E_) return;
    int u, v;
    if (*flag) { int4 w = ((const int4*)edges)[e]; u = w.x; v = w.z; }
    else       { int2 w = ((const int2*)edges)[e]; u = w.x; v = w.y; }
    float q0 = qg[0], q1 = qg[1], q2 = qg[2], q3 = qg[3];
    out[0 * (size_t)(E_ + 1) + e] = q0 + qi[0 * N_ + u] + qj[0 * N_ + v];
    out[1 * (size_t)(E_ + 1) + e] = q1 + qi[1 * N_ + u] + qj[1 * N_ + v];
    out[2 * (size_t)(E_ + 1) + e] = q2 + qi[2 * N_ + u] + qj[2 * N_ + v];
    out[3 * (size_t)(E_ + 1) + e] = q3 + qi[3 * N_ + u] + qj[3 * N_ + v];
}

extern "C" void kernel_launch(void* const* d_in, const int* in_sizes, int n_in,
                              void* d_out, int out_size, void* d_ws, size_t ws_size,
                              hipStream_t stream)
{
    const float* emb   = (const float*)d_in[0];
    const int*   edges = (const int*)d_in[1];
    const float* W6    = (const float*)d_in[2];
    const float* W7    = (const float*)d_in[3];
    const float* w5    = (const float*)d_in[4];
    const float* wno   = (const float*)d_in[5];
    float* out = (float*)d_out;

    float* W = (float*)d_ws;
    int*    flag  = (int*)W;
    float*  qg    = W + 8;
    float*  g     = W + 128;
    bf16x8* w7f   = (bf16x8*)(W + 1024);
    float*  gpart = W + 9216;
    float*  qi    = W + 649216;
    float*  qj    = W + 729216;

    hipLaunchKernelGGL(k_prep, dim3(9), dim3(256), 0, stream,
                       W7, (const unsigned*)edges, flag, g, w7f);
    hipLaunchKernelGGL(k_main, dim3(GX_, B_), dim3(256), 0, stream,
                       emb, w7f, w5, gpart, qi, qj);
    hipLaunchKernelGGL(k_greduce, dim3(50), dim3(512), 0, stream, gpart, g);
    hipLaunchKernelGGL(k_qg, dim3(B_), dim3(256), 0, stream,
                       g, W6, w5, wno, qg, out);
    hipLaunchKernelGGL(k_edge, dim3((E_ + 255) / 256), dim3(256), 0, stream,
                       edges, flag, qg, qi, qj, out);
}